// Round 3
// baseline (328.861 us; speedup 1.0000x reference)
//
#include <hip/hip_runtime.h>
#include <stdint.h>

typedef unsigned short u16;
typedef __attribute__((ext_vector_type(8))) __bf16 bf16x8;
typedef __attribute__((ext_vector_type(4))) float f32x4;

#define BSD 6291456   // 4*2048*768
#define WSZ 589824    // 768*768
#define QSCALE 0.18033688011112042f   // log2(e)/8, folded into Q projection

#if __has_builtin(__builtin_amdgcn_exp2f)
#define EXP2(x) __builtin_amdgcn_exp2f(x)
#else
#define EXP2(x) __builtin_exp2f(x)
#endif

__device__ __forceinline__ uint32_t fbits(float f) {
  union { float f; uint32_t u; } v; v.f = f; return v.u;
}
__device__ __forceinline__ u16 f2bf(float f) {           // RNE (epilogue scalar use only)
  uint32_t u = fbits(f);
  return (u16)((u + 0x7fff + ((u >> 16) & 1)) >> 16);
}
// round-to-nearest (half-up) bf16 pack of two floats via v_perm_b32: 3 insts / 2 values
__device__ __forceinline__ uint32_t pack_bf16rn(float lo, float hi) {
  return __builtin_amdgcn_perm(fbits(hi) + 0x8000u, fbits(lo) + 0x8000u, 0x07060302u);
}

__device__ __forceinline__ void load_lds16(const u16* g, u16* l) {
  __builtin_amdgcn_global_load_lds((__attribute__((address_space(1))) void*)(void*)g,
                                   (__attribute__((address_space(3))) void*)l, 16, 0, 0);
}

__device__ __forceinline__ f32x4 mfma16(bf16x8 a, bf16x8 b, f32x4 c) {
  return __builtin_amdgcn_mfma_f32_16x16x32_bf16(a, b, c, 0, 0, 0);
}

// ---------------- fp32 -> bf16 conversion of q,k,v + 4 weights ----------------
__global__ void convert_all(const float* __restrict__ q, const float* __restrict__ k,
                            const float* __restrict__ v, const float* __restrict__ wq,
                            const float* __restrict__ wk, const float* __restrict__ wv,
                            const float* __restrict__ wd, u16* __restrict__ ws) {
  long e = ((long)blockIdx.x * blockDim.x + threadIdx.x) * 8;
  const float* src;
  if (e < (long)BSD) src = q + e;
  else if (e < 2L*BSD) src = k + (e - (long)BSD);
  else if (e < 3L*BSD) src = v + (e - 2L*BSD);
  else {
    long r = e - 3L*BSD;
    if (r < (long)WSZ) src = wq + r;
    else if (r < 2L*WSZ) src = wk + (r - (long)WSZ);
    else if (r < 3L*WSZ) src = wv + (r - 2L*WSZ);
    else src = wd + (r - 3L*WSZ);
  }
  float4 f0 = ((const float4*)src)[0];
  float4 f1 = ((const float4*)src)[1];
  uint4 o;
  o.x = pack_bf16rn(f0.x, f0.y);
  o.y = pack_bf16rn(f0.z, f0.w);
  o.z = pack_bf16rn(f1.x, f1.y);
  o.w = pack_bf16rn(f1.z, f1.w);
  *(uint4*)(ws + e) = o;
}

// ---------------- C = A @ B^T (m97-style 128x128xBK32) ----------------
// MODE 0: bf16 C = val*oscale, row-major [M,N]
// MODE 1: f32  C = val + bias[c]
// MODE 2: bf16 written TRANSPOSED into Vt [B=4, H=12, 64, 2048] (packed 8B stores)
// BSEL 1: fused Q+K projection — rows >= 8192 use Bw+WSZ (wk) and scale 1
template<int MODE, int BSEL>
__global__ __launch_bounds__(256) void gemm_bt(const u16* __restrict__ A, const u16* __restrict__ Bw,
                                               u16* __restrict__ Cb, float* __restrict__ Cf,
                                               const float* __restrict__ bias,
                                               int M, int N, int K, float oscale) {
  __shared__ u16 ldsA[128*32];
  __shared__ u16 ldsB[128*32];
  const int t = threadIdx.x, w = t >> 6, lane = t & 63, quad = lane >> 4, n16 = lane & 15;
  const int m0 = blockIdx.x * 128, n0 = blockIdx.y * 128;
  const int wr = (w >> 1) * 64, wc = (w & 1) * 64;
  const u16* Bm = Bw;
  float sc = oscale;
  if (BSEL && m0 >= 8192) { Bm = Bw + WSZ; sc = 1.0f; }
  f32x4 acc[4][4] = {};
  for (int k0 = 0; k0 < K; k0 += 32) {
    __syncthreads();
#pragma unroll
    for (int j = 0; j < 2; ++j) {
      int slot = j*256 + w*64 + lane;        // lane-linear LDS dst
      int row = slot >> 2, ch = slot & 3;
      load_lds16(A  + (size_t)(m0 + row)*K + k0 + ch*8, ldsA + slot*8);
      load_lds16(Bm + (size_t)(n0 + row)*K + k0 + ch*8, ldsB + slot*8);
    }
    __syncthreads();
    bf16x8 af[4], bf[4];
#pragma unroll
    for (int i = 0; i < 4; ++i) {
      af[i] = *(const bf16x8*)(ldsA + (wr + i*16 + n16)*32 + quad*8);
      bf[i] = *(const bf16x8*)(ldsB + (wc + i*16 + n16)*32 + quad*8);
    }
#pragma unroll
    for (int mi = 0; mi < 4; ++mi)
#pragma unroll
      for (int ni = 0; ni < 4; ++ni)
        acc[mi][ni] = mfma16(af[mi], bf[ni], acc[mi][ni]);
  }
#pragma unroll
  for (int mi = 0; mi < 4; ++mi)
#pragma unroll
    for (int ni = 0; ni < 4; ++ni) {
      if (MODE == 2) {
        int c = n0 + wc + ni*16 + n16;                 // feature 0..767
        int hh = c >> 6, d = c & 63;
        int m = m0 + wr + mi*16 + quad*4;              // 4 consecutive tokens
        int bI = m >> 11, s = m & 2047;
        uint2 pk;
        pk.x = pack_bf16rn(acc[mi][ni][0], acc[mi][ni][1]);
        pk.y = pack_bf16rn(acc[mi][ni][2], acc[mi][ni][3]);
        *(uint2*)(Cb + ((size_t)(bI*12 + hh)*64 + d)*2048 + s) = pk;
      } else {
#pragma unroll
        for (int i = 0; i < 4; ++i) {
          size_t r = (size_t)m0 + wr + mi*16 + quad*4 + i;   // C/D: row=(lane>>4)*4+i
          size_t c = (size_t)n0 + wc + ni*16 + n16;          //      col=lane&15
          float val = acc[mi][ni][i];
          if (MODE == 1) Cf[r*(size_t)N + c] = val + bias[c];
          else           Cb[r*(size_t)N + c] = f2bf(val * sc);
        }
      }
    }
}

// ---------------- fused attention, round 6: occupancy package ----------------
// Round-2 counters: MfmaUtil 34 / VALUBusy 35 / Occupancy 26 — latency-bound, both
// pipes idle >60%. Grid was 768 = exactly 3 blocks/CU AND LDS 48KB capped at 3.
// Changes:
//   * QBLK 128 -> 64 (each wave owns 16 q-rows): grid 1536 blocks, ldsP halves
//     to 8KB -> LDS 40KB -> 4 blocks/CU resident, 16 waves/CU (50% static).
//   * XCD-aware swizzle: all 32 q-blocks of one (b,h) pair land on one XCD
//     (lid = (hw%8)*192 + hw/8; 1536%8==0 -> bijective). K/V fetched ~once per
//     XCD per pair, so doubling the block count does NOT double HBM traffic,
//     and staging prefetches become L2 hits (~200cyc vs ~900).
// Structure otherwise identical to the verified round-2 kernel (S^T=K.Q^T swap,
// XOR-swizzled K/V/P, MFMA rowsum via P@ones, native-cast bf16 pack).
__global__ __launch_bounds__(256, 4) void attn_fused(const u16* __restrict__ Qh, const u16* __restrict__ Kh,
                                                     const u16* __restrict__ Vt, u16* __restrict__ ctx,
                                                     float* __restrict__ rowsum) {
  __shared__ u16 ldsK[2][64*64];   // [n][8 chunks of 8 u16], chunk XOR-swizzled by n&7
  __shared__ u16 ldsV[2][64*64];   // [d][8 chunks],          swizzled by d&7
  __shared__ u16 ldsP[64*64];      // [m][8 b128-chunks],     swizzled by m&7; wave-private rows
  // XCD swizzle: hw blocks with equal (hw%8) run on the same XCD (round-robin
  // dispatch). Give each such set a contiguous logical range -> one (b,h) pair's
  // 32 q-blocks share an XCD and its L2 copy of K/V.
  const int lid = ((int)blockIdx.x & 7) * 192 + ((int)blockIdx.x >> 3);
  const int pair = lid >> 5;            // 0..47
  const int j = lid & 31;               // q-tile index
  const int h = pair % 12, b = pair / 12;
  const int q0 = j * 64;
  const int t = threadIdx.x, w = t >> 6, lane = t & 63, quad = lane >> 4, n16 = lane & 15;
  const int sw = n16 & 7;
  const u16* Kbh = Kh + (size_t)b*2048*768 + h*64;
  const u16* Vbh = Vt + (size_t)(b*12 + h)*64*2048;
  auto stage = [&](int c, int bsel) {
#pragma unroll
    for (int jj = 0; jj < 2; ++jj) {
      int slot = jj*256 + t;                // lane-linear LDS dst
      int n = slot >> 3, cg = (slot & 7) ^ (n & 7);
      load_lds16(Kbh + (size_t)(c*64 + n)*768 + cg*8, &ldsK[bsel][0] + slot*8);
      load_lds16(Vbh + (size_t)n*2048 + c*64 + cg*8, &ldsV[bsel][0] + slot*8);
    }
  };
  bf16x8 qf[2];                    // Q frags (pre-scaled by log2e/8) in regs all kernel
#pragma unroll
  for (int ks = 0; ks < 2; ++ks)
    qf[ks] = *(const bf16x8*)(Qh + (size_t)(b*2048 + q0 + w*16 + n16)*768
                                 + h*64 + ks*32 + quad*8);
  // all-ones B fragment: racc += P @ ones gives rowsums on the MFMA pipe,
  // replicated across n16 and already in C-layout rows (quad*4+i).
  union { uint32_t u[4]; bf16x8 v; } onesu = {{0x3F803F80u, 0x3F803F80u, 0x3F803F80u, 0x3F803F80u}};
  const bf16x8 ones = onesu.v;
  f32x4 oacc[4] = {};
  f32x4 racc = {};
  stage(0, 0);
#pragma unroll 1
  for (int c = 0; c < 32; ++c) {
    __syncthreads();                        // chunk c staged (vmcnt drain); prior reads of buf[(c+1)&1] done
    if (c < 31) stage(c + 1, (c + 1) & 1);  // prefetch overlaps this chunk's compute
    const u16* K0 = &ldsK[c & 1][0];
    const u16* V0 = &ldsV[c & 1][0];
    f32x4 sacc[4] = {};
#pragma unroll
    for (int ni = 0; ni < 4; ++ni) {
      const u16* krow = K0 + (ni*16 + n16)*64;
      bf16x8 kf0 = *(const bf16x8*)(krow + ((0 + quad) ^ sw)*8);
      bf16x8 kf1 = *(const bf16x8*)(krow + ((4 + quad) ^ sw)*8);
      sacc[ni] = mfma16(kf0, qf[0], sacc[ni]);   // S^T = K.Q^T
      sacc[ni] = mfma16(kf1, qf[1], sacc[ni]);
    }
    // exp2 (Q pre-scaled -> 1 v_exp each) + native-cast bf16 pack (no VALU rowsum)
    {
      int m = w*16 + n16;
      u16* prow = ldsP + m*64 + (quad & 1)*4;
#pragma unroll
      for (int ni = 0; ni < 4; ++ni) {
        float p0 = EXP2(sacc[ni][0]);
        float p1 = EXP2(sacc[ni][1]);
        float p2 = EXP2(sacc[ni][2]);
        float p3 = EXP2(sacc[ni][3]);
        union { __bf16 bx[4]; uint2 v; } pk;
        pk.bx[0] = (__bf16)p0;
        pk.bx[1] = (__bf16)p1;
        pk.bx[2] = (__bf16)p2;
        pk.bx[3] = (__bf16)p3;
        int c128 = ((ni*2 + (quad >> 1)) ^ sw);
        *(uint2*)(prow + c128*8) = pk.v;
      }
    }
    // PV: A = P (wave-private rows, no barrier), B = V^T chunk; rowsum rides along
#pragma unroll
    for (int kt = 0; kt < 2; ++kt) {
      bf16x8 pf, vf[4];
      pf = *(const bf16x8*)(ldsP + (w*16 + n16)*64 + ((kt*4 + quad) ^ sw)*8);
#pragma unroll
      for (int di = 0; di < 4; ++di)
        vf[di] = *(const bf16x8*)(V0 + (di*16 + n16)*64 + ((kt*4 + quad) ^ sw)*8);
      racc = mfma16(pf, ones, racc);
#pragma unroll
      for (int di = 0; di < 4; ++di)
        oacc[di] = mfma16(pf, vf[di], oacc[di]);
    }
  }
  // racc[i] = full rowsum for row quad*4+i (replicated over n16) — matches oacc layout
  float invr[4];
#pragma unroll
  for (int i = 0; i < 4; ++i)
    invr[i] = 1.0f / racc[i];
#pragma unroll
  for (int di = 0; di < 4; ++di)
#pragma unroll
    for (int i = 0; i < 4; ++i) {
      size_t r = (size_t)b*2048 + q0 + w*16 + quad*4 + i;
      int cc = h*64 + di*16 + n16;
      ctx[r*768 + cc] = f2bf(oacc[di][i] * invr[i]);
    }
  if (h == 0 && n16 == 0) {
#pragma unroll
    for (int i = 0; i < 4; ++i)
      rowsum[b*2048 + q0 + w*16 + quad*4 + i] = racc[i];
  }
}

// ---------------- attn[:,0,:,:]: recompute QK^T for h=0, scale by 1/rowsum ----------------
__global__ __launch_bounds__(256) void attn_h0(const u16* __restrict__ Qh, const u16* __restrict__ Kh,
                                               const float* __restrict__ rowsum, float* __restrict__ aout) {
  __shared__ u16 ldsK[128*64];
  const int qt = blockIdx.x, kt = blockIdx.y, b = blockIdx.z;
  const int t = threadIdx.x, w = t >> 6, lane = t & 63, quad = lane >> 4, n16 = lane & 15;
  const int q0 = qt * 128;
  const u16* Kbh = Kh + (size_t)b*2048*768;  // h = 0
  bf16x8 qf[2][2];
#pragma unroll
  for (int mi = 0; mi < 2; ++mi)
#pragma unroll
    for (int ks = 0; ks < 2; ++ks)
      qf[mi][ks] = *(const bf16x8*)(Qh + (size_t)(b*2048 + q0 + w*32 + mi*16 + n16)*768
                                       + ks*32 + quad*8);
#pragma unroll
  for (int j = 0; j < 4; ++j) {
    int slot = j*256 + w*64 + lane;
    int n = slot >> 3, cs = slot & 7, cg = cs ^ (n & 7);
    load_lds16(Kbh + (size_t)(kt*128 + n)*768 + cg*8, ldsK + slot*8);
  }
  __syncthreads();
  f32x4 sacc[2][8] = {};
#pragma unroll
  for (int ni = 0; ni < 8; ++ni) {
    int n = ni*16 + n16;
    bf16x8 kf0 = *(const bf16x8*)(ldsK + n*64 + ((quad)     ^ (n & 7))*8);
    bf16x8 kf1 = *(const bf16x8*)(ldsK + n*64 + ((4 + quad) ^ (n & 7))*8);
#pragma unroll
    for (int mi = 0; mi < 2; ++mi) {
      sacc[mi][ni] = mfma16(qf[mi][0], kf0, sacc[mi][ni]);
      sacc[mi][ni] = mfma16(qf[mi][1], kf1, sacc[mi][ni]);
    }
  }
  float inv[2][4];
#pragma unroll
  for (int mi = 0; mi < 2; ++mi)
#pragma unroll
    for (int i = 0; i < 4; ++i)
      inv[mi][i] = 1.0f / rowsum[b*2048 + q0 + w*32 + mi*16 + quad*4 + i];
#pragma unroll
  for (int mi = 0; mi < 2; ++mi)
#pragma unroll
    for (int ni = 0; ni < 8; ++ni)
#pragma unroll
      for (int i = 0; i < 4; ++i) {
        size_t r = (size_t)b*2048 + q0 + w*32 + mi*16 + quad*4 + i;
        size_t cc = (size_t)kt*128 + ni*16 + n16;
        aout[r*2048 + cc] = EXP2(sacc[mi][ni][i]) * inv[mi][i];   // Qh pre-scaled
      }
}

extern "C" void kernel_launch(void* const* d_in, const int* in_sizes, int n_in,
                              void* d_out, int out_size, void* d_ws, size_t ws_size,
                              hipStream_t stream) {
  (void)in_sizes; (void)n_in; (void)out_size; (void)ws_size;
  const float* q  = (const float*)d_in[0];
  const float* k  = (const float*)d_in[1];
  const float* v  = (const float*)d_in[2];
  const float* wq = (const float*)d_in[3];
  const float* wk = (const float*)d_in[4];
  const float* wv = (const float*)d_in[5];
  const float* wd = (const float*)d_in[6];
  const float* bd = (const float*)d_in[7];

  // ws layout (u16 elements), high-water ~67.7 MB:
  //   qb -> Vt   (qb dead after fused QK projection; V-gemm writes Vt there)
  //   kb -> ctx  (kb dead after fused QK projection)
  u16* ws  = (u16*)d_ws;
  u16* qb  = ws;                       // rows 0..8191  of fused QK A-matrix
  u16* kb  = ws + (size_t)BSD;         // rows 8192..16383
  u16* vb  = ws + 2L*BSD;
  u16* wqb = ws + 3L*BSD;              // wq, wk contiguous (BSEL indexing)
  u16* wvb = wqb + 2L*WSZ;
  u16* wdb = wqb + 3L*WSZ;
  u16* Qh  = ws + 3L*BSD + 4L*WSZ;     // Qh, Kh contiguous (fused QK C-matrix)
  u16* Kh  = Qh + (size_t)BSD;
  float* rsum = (float*)(Kh + (size_t)BSD);
  u16* Vt  = qb;
  u16* ctx = kb;
  float* out  = (float*)d_out;
  float* aout = out + (size_t)BSD;

  convert_all<<<dim3(10368), 256, 0, stream>>>(q, k, v, wq, wk, wv, wd, ws);
  // fused Q+K projection (Q pre-scaled by log2e/8), 768 blocks = 3/CU even
  gemm_bt<0,1><<<dim3(128, 6), 256, 0, stream>>>(qb, wqb, Qh, nullptr, nullptr, 16384, 768, 768, QSCALE);
  // V projection with fused transpose into Vt
  gemm_bt<2,0><<<dim3(64, 6), 256, 0, stream>>>(vb, wvb, Vt, nullptr, nullptr, 8192, 768, 768, 1.0f);
  attn_fused<<<dim3(1536), 256, 0, stream>>>(Qh, Kh, Vt, ctx, rsum);
  attn_h0<<<dim3(16, 16, 4), 256, 0, stream>>>(Qh, Kh, rsum, aout);
  gemm_bt<1,0><<<dim3(64, 6), 256, 0, stream>>>(ctx, wdb, nullptr, out, bd, 8192, 768, 768, 1.0f);
}

// Round 4
// 317.061 us; speedup vs baseline: 1.0372x; 1.0372x over previous
//
#include <hip/hip_runtime.h>
#include <stdint.h>

typedef unsigned short u16;
typedef __attribute__((ext_vector_type(8))) __bf16 bf16x8;
typedef __attribute__((ext_vector_type(4))) float f32x4;
typedef __attribute__((ext_vector_type(2))) unsigned uint2u;

#define BSD 6291456   // 4*2048*768
#define WSZ 589824    // 768*768
#define QSCALE 0.18033688011112042f   // log2(e)/8, folded into Q projection

#if __has_builtin(__builtin_amdgcn_exp2f)
#define EXP2(x) __builtin_amdgcn_exp2f(x)
#else
#define EXP2(x) __builtin_exp2f(x)
#endif

__device__ __forceinline__ uint32_t fbits(float f) {
  union { float f; uint32_t u; } v; v.f = f; return v.u;
}
__device__ __forceinline__ u16 f2bf(float f) {           // RNE (epilogue scalar use only)
  uint32_t u = fbits(f);
  return (u16)((u + 0x7fff + ((u >> 16) & 1)) >> 16);
}
// round-to-nearest (half-up) bf16 pack of two floats via v_perm_b32: 3 insts / 2 values
__device__ __forceinline__ uint32_t pack_bf16rn(float lo, float hi) {
  return __builtin_amdgcn_perm(fbits(hi) + 0x8000u, fbits(lo) + 0x8000u, 0x07060302u);
}

__device__ __forceinline__ void load_lds16(const u16* g, u16* l) {
  __builtin_amdgcn_global_load_lds((__attribute__((address_space(1))) void*)(void*)g,
                                   (__attribute__((address_space(3))) void*)l, 16, 0, 0);
}

__device__ __forceinline__ f32x4 mfma16(bf16x8 a, bf16x8 b, f32x4 c) {
  return __builtin_amdgcn_mfma_f32_16x16x32_bf16(a, b, c, 0, 0, 0);
}

// Quad-space redistribution for the P C-layout -> PV A-frag transform.
// Inputs X = rows [X0,X1,X2,X3] (16-lane rows = quads), Y likewise.
// Outputs: ev = [X0,X2,Y0,Y2], od = [X1,X3,Y1,Y3].
// permlane32_swap(a,b): a' = [a.lo32, b.lo32], b' = [a.hi32, b.hi32]
// permlane16_swap(a,b): per row-pair, a_odd <-> b_even:
//   a' = [a_r0, b_r0, a_r2, b_r2], b' = [a_r1, b_r1, a_r3, b_r3]
// Chain: s = pl32(X,Y) -> s.x=[X0,X1,Y0,Y1], s.y=[X2,X3,Y2,Y3]
//        r = pl16(s.x,s.y) -> r.x=[X0,X2,Y0,Y2]=ev, r.y=[X1,X3,Y1,Y3]=od
__device__ __forceinline__ void pl_combine(uint32_t X, uint32_t Y,
                                           uint32_t& ev, uint32_t& od) {
#if __has_builtin(__builtin_amdgcn_permlane32_swap) && __has_builtin(__builtin_amdgcn_permlane16_swap)
  uint2u s = __builtin_amdgcn_permlane32_swap(X, Y, false, false);
  uint2u r = __builtin_amdgcn_permlane16_swap(s.x, s.y, false, false);
  ev = r.x; od = r.y;
#else
  // shfl_xor fallback (semantics certain, ~3x the ops)
  int quad = ((int)threadIdx.x & 63) >> 4;
  uint32_t x48 = __shfl_xor(X, 48), y32 = __shfl_xor(Y, 32), y16 = __shfl_xor(Y, 16);
  uint32_t x16 = __shfl_xor(X, 16), x32 = __shfl_xor(X, 32), y48 = __shfl_xor(Y, 48);
  ev = quad == 0 ? X   : quad == 1 ? x48 : quad == 2 ? y32 : y16;
  od = quad == 0 ? x16 : quad == 1 ? x32 : quad == 2 ? y48 : Y;
#endif
}

// ---------------- fp32 -> bf16 conversion of q,k,v + 4 weights ----------------
__global__ void convert_all(const float* __restrict__ q, const float* __restrict__ k,
                            const float* __restrict__ v, const float* __restrict__ wq,
                            const float* __restrict__ wk, const float* __restrict__ wv,
                            const float* __restrict__ wd, u16* __restrict__ ws) {
  long e = ((long)blockIdx.x * blockDim.x + threadIdx.x) * 8;
  const float* src;
  if (e < (long)BSD) src = q + e;
  else if (e < 2L*BSD) src = k + (e - (long)BSD);
  else if (e < 3L*BSD) src = v + (e - 2L*BSD);
  else {
    long r = e - 3L*BSD;
    if (r < (long)WSZ) src = wq + r;
    else if (r < 2L*WSZ) src = wk + (r - (long)WSZ);
    else if (r < 3L*WSZ) src = wv + (r - 2L*WSZ);
    else src = wd + (r - 3L*WSZ);
  }
  float4 f0 = ((const float4*)src)[0];
  float4 f1 = ((const float4*)src)[1];
  uint4 o;
  o.x = pack_bf16rn(f0.x, f0.y);
  o.y = pack_bf16rn(f0.z, f0.w);
  o.z = pack_bf16rn(f1.x, f1.y);
  o.w = pack_bf16rn(f1.z, f1.w);
  *(uint4*)(ws + e) = o;
}

// ---------------- C = A @ B^T (m97-style 128x128xBK32) ----------------
// MODE 0: bf16 C = val*oscale, row-major [M,N]
// MODE 1: f32  C = val + bias[c]
// MODE 2: bf16 written TRANSPOSED into Vt [B=4, H=12, 64, 2048] (packed 8B stores)
// BSEL 1: fused Q+K projection — rows >= 8192 use Bw+WSZ (wk) and scale 1
template<int MODE, int BSEL>
__global__ __launch_bounds__(256) void gemm_bt(const u16* __restrict__ A, const u16* __restrict__ Bw,
                                               u16* __restrict__ Cb, float* __restrict__ Cf,
                                               const float* __restrict__ bias,
                                               int M, int N, int K, float oscale) {
  __shared__ u16 ldsA[128*32];
  __shared__ u16 ldsB[128*32];
  const int t = threadIdx.x, w = t >> 6, lane = t & 63, quad = lane >> 4, n16 = lane & 15;
  const int m0 = blockIdx.x * 128, n0 = blockIdx.y * 128;
  const int wr = (w >> 1) * 64, wc = (w & 1) * 64;
  const u16* Bm = Bw;
  float sc = oscale;
  if (BSEL && m0 >= 8192) { Bm = Bw + WSZ; sc = 1.0f; }
  f32x4 acc[4][4] = {};
  for (int k0 = 0; k0 < K; k0 += 32) {
    __syncthreads();
#pragma unroll
    for (int j = 0; j < 2; ++j) {
      int slot = j*256 + w*64 + lane;        // lane-linear LDS dst
      int row = slot >> 2, ch = slot & 3;
      load_lds16(A  + (size_t)(m0 + row)*K + k0 + ch*8, ldsA + slot*8);
      load_lds16(Bm + (size_t)(n0 + row)*K + k0 + ch*8, ldsB + slot*8);
    }
    __syncthreads();
    bf16x8 af[4], bf[4];
#pragma unroll
    for (int i = 0; i < 4; ++i) {
      af[i] = *(const bf16x8*)(ldsA + (wr + i*16 + n16)*32 + quad*8);
      bf[i] = *(const bf16x8*)(ldsB + (wc + i*16 + n16)*32 + quad*8);
    }
#pragma unroll
    for (int mi = 0; mi < 4; ++mi)
#pragma unroll
      for (int ni = 0; ni < 4; ++ni)
        acc[mi][ni] = mfma16(af[mi], bf[ni], acc[mi][ni]);
  }
#pragma unroll
  for (int mi = 0; mi < 4; ++mi)
#pragma unroll
    for (int ni = 0; ni < 4; ++ni) {
      if (MODE == 2) {
        int c = n0 + wc + ni*16 + n16;                 // feature 0..767
        int hh = c >> 6, d = c & 63;
        int m = m0 + wr + mi*16 + quad*4;              // 4 consecutive tokens
        int bI = m >> 11, s = m & 2047;
        uint2 pk;
        pk.x = pack_bf16rn(acc[mi][ni][0], acc[mi][ni][1]);
        pk.y = pack_bf16rn(acc[mi][ni][2], acc[mi][ni][3]);
        *(uint2*)(Cb + ((size_t)(bI*12 + hh)*64 + d)*2048 + s) = pk;
      } else {
#pragma unroll
        for (int i = 0; i < 4; ++i) {
          size_t r = (size_t)m0 + wr + mi*16 + quad*4 + i;   // C/D: row=(lane>>4)*4+i
          size_t c = (size_t)n0 + wc + ni*16 + n16;          //      col=lane&15
          float val = acc[mi][ni][i];
          if (MODE == 1) Cf[r*(size_t)N + c] = val + bias[c];
          else           Cb[r*(size_t)N + c] = f2bf(val * sc);
        }
      }
    }
}

// ---------------- fused attention, round 7: P-in-register (no ldsP) ----------------
// Round-3 analysis: LDS traffic is ~55-60% of per-chunk time (336KB/CU/chunk vs
// ~115 B/cyc); r3's QBLK=64 regression (+70% LDS traffic -> +25% dur) confirmed.
// Changes vs the verified round-2 kernel:
//   * P never touches LDS. S^T C-layout (lane: P[q=n16][k=ni*16+quad*4+i]) is
//     permuted in quad-space to the PV A-frag (k=kt*32+quad*8+j) with
//     permlane32_swap + permlane16_swap pairs (see pl_combine). Removes
//     8 ds_write_b64 + 4 ds_read_b128 per wave per chunk (~29% of LDS traffic)
//     and the write->lgkmcnt->read chain segment. ldsP freed: LDS 48->32KB.
//   * XCD-aware swizzle (proven in r3: FETCH 104->18.5MB): 1D grid 768,
//     lid=(bid&7)*96+(bid>>3) bijective; 6 (b,h) pairs per XCD -> 3MB K/V in L2.
//   * QBLK stays 128 (r3 lesson: smaller q-tiles duplicate K/V LDS reads).
__global__ __launch_bounds__(256, 3) void attn_fused(const u16* __restrict__ Qh, const u16* __restrict__ Kh,
                                                     const u16* __restrict__ Vt, u16* __restrict__ ctx,
                                                     float* __restrict__ rowsum) {
  __shared__ u16 ldsK[2][64*64];   // [n][8 chunks of 8 u16], chunk XOR-swizzled by n&7
  __shared__ u16 ldsV[2][64*64];   // [d][8 chunks],          swizzled by d&7
  const int bid = blockIdx.x;
  const int lid = (bid & 7) * 96 + (bid >> 3);   // XCD-contiguous logical id
  const int pair = lid >> 4;            // 0..47 = (b,h)
  const int qt = lid & 15;              // q-tile
  const int h = pair % 12, b = pair / 12;
  const int q0 = qt * 128;
  const int t = threadIdx.x, w = t >> 6, lane = t & 63, quad = lane >> 4, n16 = lane & 15;
  const int sw = n16 & 7;
  const u16* Kbh = Kh + (size_t)b*2048*768 + h*64;
  const u16* Vbh = Vt + (size_t)(b*12 + h)*64*2048;
  auto stage = [&](int c, int bsel) {
#pragma unroll
    for (int jj = 0; jj < 2; ++jj) {
      int slot = jj*256 + t;                // lane-linear LDS dst
      int n = slot >> 3, cg = (slot & 7) ^ (n & 7);
      load_lds16(Kbh + (size_t)(c*64 + n)*768 + cg*8, &ldsK[bsel][0] + slot*8);
      load_lds16(Vbh + (size_t)n*2048 + c*64 + cg*8, &ldsV[bsel][0] + slot*8);
    }
  };
  bf16x8 qf[2][2];                 // Q frags (pre-scaled by log2e/8) in regs all kernel
#pragma unroll
  for (int mi = 0; mi < 2; ++mi)
#pragma unroll
    for (int ks = 0; ks < 2; ++ks)
      qf[mi][ks] = *(const bf16x8*)(Qh + (size_t)(b*2048 + q0 + w*32 + mi*16 + n16)*768
                                       + h*64 + ks*32 + quad*8);
  // all-ones B fragment: racc += P @ ones gives rowsums on the MFMA pipe,
  // replicated across n16 and already in C-layout rows (quad*4+i).
  union { uint32_t u[4]; bf16x8 v; } onesu = {{0x3F803F80u, 0x3F803F80u, 0x3F803F80u, 0x3F803F80u}};
  const bf16x8 ones = onesu.v;
  f32x4 oacc[2][4] = {};
  f32x4 racc[2] = {};
  stage(0, 0);
#pragma unroll 1
  for (int c = 0; c < 32; ++c) {
    __syncthreads();                        // chunk c staged (vmcnt drain); prior reads of buf[(c+1)&1] done
    if (c < 31) stage(c + 1, (c + 1) & 1);  // prefetch overlaps this chunk's compute
    const u16* K0 = &ldsK[c & 1][0];
    const u16* V0 = &ldsV[c & 1][0];
    f32x4 sacc[4][2] = {};
#pragma unroll
    for (int ni = 0; ni < 4; ++ni) {
      const u16* krow = K0 + (ni*16 + n16)*64;
      bf16x8 kf0 = *(const bf16x8*)(krow + ((0 + quad) ^ sw)*8);
      bf16x8 kf1 = *(const bf16x8*)(krow + ((4 + quad) ^ sw)*8);
#pragma unroll
      for (int mi = 0; mi < 2; ++mi) {
        sacc[ni][mi] = mfma16(kf0, qf[mi][0], sacc[ni][mi]);   // S^T = K.Q^T
        sacc[ni][mi] = mfma16(kf1, qf[mi][1], sacc[ni][mi]);
      }
    }
    // exp2 (Q pre-scaled -> 1 v_exp each) + native-cast bf16 pack into registers
    uint32_t pd0[2][4], pd1[2][4];   // [mi][ni]: (p0,p1) and (p2,p3) bf16 pairs
#pragma unroll
    for (int mi = 0; mi < 2; ++mi)
#pragma unroll
      for (int ni = 0; ni < 4; ++ni) {
        float p0 = EXP2(sacc[ni][mi][0]);
        float p1 = EXP2(sacc[ni][mi][1]);
        float p2 = EXP2(sacc[ni][mi][2]);
        float p3 = EXP2(sacc[ni][mi][3]);
        union { __bf16 bx[2]; uint32_t v; } lo, hi;
        lo.bx[0] = (__bf16)p0; lo.bx[1] = (__bf16)p1;
        hi.bx[0] = (__bf16)p2; hi.bx[1] = (__bf16)p3;
        pd0[mi][ni] = lo.v;
        pd1[mi][ni] = hi.v;
      }
    // quad-space permute: C-layout k=ni*16+quad*4+i  ->  A-frag k=kt*32+quad*8+j
    bf16x8 pf[2][2];   // [mi][kt]
#pragma unroll
    for (int mi = 0; mi < 2; ++mi)
#pragma unroll
      for (int kt = 0; kt < 2; ++kt) {
        uint32_t e0, o0, e1, o1;
        pl_combine(pd0[mi][kt*2], pd0[mi][kt*2 + 1], e0, o0);
        pl_combine(pd1[mi][kt*2], pd1[mi][kt*2 + 1], e1, o1);
        union { uint32_t u[4]; bf16x8 v; } fr;
        fr.u[0] = e0; fr.u[1] = e1; fr.u[2] = o0; fr.u[3] = o1;
        pf[mi][kt] = fr.v;
      }
    // PV: A = P (in registers), B = V^T chunk; rowsum rides along on MFMA pipe
#pragma unroll
    for (int kt = 0; kt < 2; ++kt) {
      bf16x8 vf[4];
#pragma unroll
      for (int di = 0; di < 4; ++di)
        vf[di] = *(const bf16x8*)(V0 + (di*16 + n16)*64 + ((kt*4 + quad) ^ sw)*8);
#pragma unroll
      for (int mi = 0; mi < 2; ++mi) {
        racc[mi] = mfma16(pf[mi][kt], ones, racc[mi]);
#pragma unroll
        for (int di = 0; di < 4; ++di)
          oacc[mi][di] = mfma16(pf[mi][kt], vf[di], oacc[mi][di]);
      }
    }
  }
  // racc[mi][i] = full rowsum for row quad*4+i (replicated over n16) — matches oacc layout
  float invr[2][4];
#pragma unroll
  for (int mi = 0; mi < 2; ++mi)
#pragma unroll
    for (int i = 0; i < 4; ++i)
      invr[mi][i] = 1.0f / racc[mi][i];
#pragma unroll
  for (int mi = 0; mi < 2; ++mi)
#pragma unroll
    for (int di = 0; di < 4; ++di)
#pragma unroll
      for (int i = 0; i < 4; ++i) {
        size_t r = (size_t)b*2048 + q0 + w*32 + mi*16 + quad*4 + i;
        int cc = h*64 + di*16 + n16;
        ctx[r*768 + cc] = f2bf(oacc[mi][di][i] * invr[mi][i]);
      }
  if (h == 0 && n16 == 0) {
#pragma unroll
    for (int mi = 0; mi < 2; ++mi)
#pragma unroll
      for (int i = 0; i < 4; ++i)
        rowsum[b*2048 + q0 + w*32 + mi*16 + quad*4 + i] = racc[mi][i];
  }
}

// ---------------- attn[:,0,:,:]: recompute QK^T for h=0, scale by 1/rowsum ----------------
__global__ __launch_bounds__(256) void attn_h0(const u16* __restrict__ Qh, const u16* __restrict__ Kh,
                                               const float* __restrict__ rowsum, float* __restrict__ aout) {
  __shared__ u16 ldsK[128*64];
  const int qt = blockIdx.x, kt = blockIdx.y, b = blockIdx.z;
  const int t = threadIdx.x, w = t >> 6, lane = t & 63, quad = lane >> 4, n16 = lane & 15;
  const int q0 = qt * 128;
  const u16* Kbh = Kh + (size_t)b*2048*768;  // h = 0
  bf16x8 qf[2][2];
#pragma unroll
  for (int mi = 0; mi < 2; ++mi)
#pragma unroll
    for (int ks = 0; ks < 2; ++ks)
      qf[mi][ks] = *(const bf16x8*)(Qh + (size_t)(b*2048 + q0 + w*32 + mi*16 + n16)*768
                                       + ks*32 + quad*8);
#pragma unroll
  for (int j = 0; j < 4; ++j) {
    int slot = j*256 + w*64 + lane;
    int n = slot >> 3, cs = slot & 7, cg = cs ^ (n & 7);
    load_lds16(Kbh + (size_t)(kt*128 + n)*768 + cg*8, ldsK + slot*8);
  }
  __syncthreads();
  f32x4 sacc[2][8] = {};
#pragma unroll
  for (int ni = 0; ni < 8; ++ni) {
    int n = ni*16 + n16;
    bf16x8 kf0 = *(const bf16x8*)(ldsK + n*64 + ((quad)     ^ (n & 7))*8);
    bf16x8 kf1 = *(const bf16x8*)(ldsK + n*64 + ((4 + quad) ^ (n & 7))*8);
#pragma unroll
    for (int mi = 0; mi < 2; ++mi) {
      sacc[mi][ni] = mfma16(qf[mi][0], kf0, sacc[mi][ni]);
      sacc[mi][ni] = mfma16(qf[mi][1], kf1, sacc[mi][ni]);
    }
  }
  float inv[2][4];
#pragma unroll
  for (int mi = 0; mi < 2; ++mi)
#pragma unroll
    for (int i = 0; i < 4; ++i)
      inv[mi][i] = 1.0f / rowsum[b*2048 + q0 + w*32 + mi*16 + quad*4 + i];
#pragma unroll
  for (int mi = 0; mi < 2; ++mi)
#pragma unroll
    for (int ni = 0; ni < 8; ++ni)
#pragma unroll
      for (int i = 0; i < 4; ++i) {
        size_t r = (size_t)b*2048 + q0 + w*32 + mi*16 + quad*4 + i;
        size_t cc = (size_t)kt*128 + ni*16 + n16;
        aout[r*2048 + cc] = EXP2(sacc[mi][ni][i]) * inv[mi][i];   // Qh pre-scaled
      }
}

extern "C" void kernel_launch(void* const* d_in, const int* in_sizes, int n_in,
                              void* d_out, int out_size, void* d_ws, size_t ws_size,
                              hipStream_t stream) {
  (void)in_sizes; (void)n_in; (void)out_size; (void)ws_size;
  const float* q  = (const float*)d_in[0];
  const float* k  = (const float*)d_in[1];
  const float* v  = (const float*)d_in[2];
  const float* wq = (const float*)d_in[3];
  const float* wk = (const float*)d_in[4];
  const float* wv = (const float*)d_in[5];
  const float* wd = (const float*)d_in[6];
  const float* bd = (const float*)d_in[7];

  // ws layout (u16 elements), high-water ~67.7 MB:
  //   qb -> Vt   (qb dead after fused QK projection; V-gemm writes Vt there)
  //   kb -> ctx  (kb dead after fused QK projection)
  u16* ws  = (u16*)d_ws;
  u16* qb  = ws;                       // rows 0..8191  of fused QK A-matrix
  u16* kb  = ws + (size_t)BSD;         // rows 8192..16383
  u16* vb  = ws + 2L*BSD;
  u16* wqb = ws + 3L*BSD;              // wq, wk contiguous (BSEL indexing)
  u16* wvb = wqb + 2L*WSZ;
  u16* wdb = wqb + 3L*WSZ;
  u16* Qh  = ws + 3L*BSD + 4L*WSZ;     // Qh, Kh contiguous (fused QK C-matrix)
  u16* Kh  = Qh + (size_t)BSD;
  float* rsum = (float*)(Kh + (size_t)BSD);
  u16* Vt  = qb;
  u16* ctx = kb;
  float* out  = (float*)d_out;
  float* aout = out + (size_t)BSD;

  convert_all<<<dim3(10368), 256, 0, stream>>>(q, k, v, wq, wk, wv, wd, ws);
  // fused Q+K projection (Q pre-scaled by log2e/8), 768 blocks = 3/CU even
  gemm_bt<0,1><<<dim3(128, 6), 256, 0, stream>>>(qb, wqb, Qh, nullptr, nullptr, 16384, 768, 768, QSCALE);
  // V projection with fused transpose into Vt
  gemm_bt<2,0><<<dim3(64, 6), 256, 0, stream>>>(vb, wvb, Vt, nullptr, nullptr, 8192, 768, 768, 1.0f);
  attn_fused<<<dim3(768), 256, 0, stream>>>(Qh, Kh, Vt, ctx, rsum);
  attn_h0<<<dim3(16, 16, 4), 256, 0, stream>>>(Qh, Kh, rsum, aout);
  gemm_bt<1,0><<<dim3(64, 6), 256, 0, stream>>>(ctx, wdb, nullptr, out, bd, 8192, 768, 768, 1.0f);
}

// Round 5
// 309.706 us; speedup vs baseline: 1.0618x; 1.0237x over previous
//
#include <hip/hip_runtime.h>
#include <stdint.h>

typedef unsigned short u16;
typedef __attribute__((ext_vector_type(8))) __bf16 bf16x8;
typedef __attribute__((ext_vector_type(4))) float f32x4;

#define BSD 6291456   // 4*2048*768
#define WSZ 589824    // 768*768
#define QSCALE 0.18033688011112042f   // log2(e)/8, folded into Q projection

#if __has_builtin(__builtin_amdgcn_exp2f)
#define EXP2(x) __builtin_amdgcn_exp2f(x)
#else
#define EXP2(x) __builtin_exp2f(x)
#endif

__device__ __forceinline__ uint32_t fbits(float f) {
  union { float f; uint32_t u; } v; v.f = f; return v.u;
}
__device__ __forceinline__ u16 f2bf(float f) {           // RNE (epilogue scalar use only)
  uint32_t u = fbits(f);
  return (u16)((u + 0x7fff + ((u >> 16) & 1)) >> 16);
}
// round-to-nearest (half-up) bf16 pack of two floats via v_perm_b32: 3 insts / 2 values
__device__ __forceinline__ uint32_t pack_bf16rn(float lo, float hi) {
  return __builtin_amdgcn_perm(fbits(hi) + 0x8000u, fbits(lo) + 0x8000u, 0x07060302u);
}

__device__ __forceinline__ void load_lds16(const u16* g, u16* l) {
  __builtin_amdgcn_global_load_lds((__attribute__((address_space(1))) void*)(void*)g,
                                   (__attribute__((address_space(3))) void*)l, 16, 0, 0);
}

__device__ __forceinline__ f32x4 mfma16(bf16x8 a, bf16x8 b, f32x4 c) {
  return __builtin_amdgcn_mfma_f32_16x16x32_bf16(a, b, c, 0, 0, 0);
}

// ---------------- fp32 -> bf16 conversion of q,k,v + 4 weights ----------------
__global__ void convert_all(const float* __restrict__ q, const float* __restrict__ k,
                            const float* __restrict__ v, const float* __restrict__ wq,
                            const float* __restrict__ wk, const float* __restrict__ wv,
                            const float* __restrict__ wd, u16* __restrict__ ws) {
  long e = ((long)blockIdx.x * blockDim.x + threadIdx.x) * 8;
  const float* src;
  if (e < (long)BSD) src = q + e;
  else if (e < 2L*BSD) src = k + (e - (long)BSD);
  else if (e < 3L*BSD) src = v + (e - 2L*BSD);
  else {
    long r = e - 3L*BSD;
    if (r < (long)WSZ) src = wq + r;
    else if (r < 2L*WSZ) src = wk + (r - (long)WSZ);
    else if (r < 3L*WSZ) src = wv + (r - 2L*WSZ);
    else src = wd + (r - 3L*WSZ);
  }
  float4 f0 = ((const float4*)src)[0];
  float4 f1 = ((const float4*)src)[1];
  uint4 o;
  o.x = pack_bf16rn(f0.x, f0.y);
  o.y = pack_bf16rn(f0.z, f0.w);
  o.z = pack_bf16rn(f1.x, f1.y);
  o.w = pack_bf16rn(f1.z, f1.w);
  *(uint4*)(ws + e) = o;
}

// ---------------- C = A @ B^T (m97-style 128x128xBK32) ----------------
// MODE 0: bf16 C = val*oscale, row-major [M,N]
// MODE 1: f32  C = val + bias[c]
// MODE 2: bf16 written TRANSPOSED into Vt [B=4, H=12, 64, 2048] (packed 8B stores)
// BSEL 1: fused Q+K projection — rows >= 8192 use Bw+WSZ (wk) and scale 1
template<int MODE, int BSEL>
__global__ __launch_bounds__(256) void gemm_bt(const u16* __restrict__ A, const u16* __restrict__ Bw,
                                               u16* __restrict__ Cb, float* __restrict__ Cf,
                                               const float* __restrict__ bias,
                                               int M, int N, int K, float oscale) {
  __shared__ u16 ldsA[128*32];
  __shared__ u16 ldsB[128*32];
  const int t = threadIdx.x, w = t >> 6, lane = t & 63, quad = lane >> 4, n16 = lane & 15;
  const int m0 = blockIdx.x * 128, n0 = blockIdx.y * 128;
  const int wr = (w >> 1) * 64, wc = (w & 1) * 64;
  const u16* Bm = Bw;
  float sc = oscale;
  if (BSEL && m0 >= 8192) { Bm = Bw + WSZ; sc = 1.0f; }
  f32x4 acc[4][4] = {};
  for (int k0 = 0; k0 < K; k0 += 32) {
    __syncthreads();
#pragma unroll
    for (int j = 0; j < 2; ++j) {
      int slot = j*256 + w*64 + lane;        // lane-linear LDS dst
      int row = slot >> 2, ch = slot & 3;
      load_lds16(A  + (size_t)(m0 + row)*K + k0 + ch*8, ldsA + slot*8);
      load_lds16(Bm + (size_t)(n0 + row)*K + k0 + ch*8, ldsB + slot*8);
    }
    __syncthreads();
    bf16x8 af[4], bf[4];
#pragma unroll
    for (int i = 0; i < 4; ++i) {
      af[i] = *(const bf16x8*)(ldsA + (wr + i*16 + n16)*32 + quad*8);
      bf[i] = *(const bf16x8*)(ldsB + (wc + i*16 + n16)*32 + quad*8);
    }
#pragma unroll
    for (int mi = 0; mi < 4; ++mi)
#pragma unroll
      for (int ni = 0; ni < 4; ++ni)
        acc[mi][ni] = mfma16(af[mi], bf[ni], acc[mi][ni]);
  }
#pragma unroll
  for (int mi = 0; mi < 4; ++mi)
#pragma unroll
    for (int ni = 0; ni < 4; ++ni) {
      if (MODE == 2) {
        int c = n0 + wc + ni*16 + n16;                 // feature 0..767
        int hh = c >> 6, d = c & 63;
        int m = m0 + wr + mi*16 + quad*4;              // 4 consecutive tokens
        int bI = m >> 11, s = m & 2047;
        uint2 pk;
        pk.x = pack_bf16rn(acc[mi][ni][0], acc[mi][ni][1]);
        pk.y = pack_bf16rn(acc[mi][ni][2], acc[mi][ni][3]);
        *(uint2*)(Cb + ((size_t)(bI*12 + hh)*64 + d)*2048 + s) = pk;
      } else {
#pragma unroll
        for (int i = 0; i < 4; ++i) {
          size_t r = (size_t)m0 + wr + mi*16 + quad*4 + i;   // C/D: row=(lane>>4)*4+i
          size_t c = (size_t)n0 + wc + ni*16 + n16;          //      col=lane&15
          float val = acc[mi][ni][i];
          if (MODE == 1) Cf[r*(size_t)N + c] = val + bias[c];
          else           Cb[r*(size_t)N + c] = f2bf(val * sc);
        }
      }
    }
}

// ---------------- fused attention, round 8: r2 structure + swizzle + address diet ----
// r4 post-mortem: LDS BW was NOT the bottleneck (cutting it 43% + conflicts->0 didn't
// help; P-in-reg permlane fell back to shfl and cost +15pt VALU). r2's wall = ~35%
// VALU + ~20% LDS + ~7% MFMA issue + ~38% latency/sync dead time at 3 waves/SIMD.
// This round keeps the verified r2 structure (LDS-P, MFMA rowsum, native pack) and:
//   * XCD-aware swizzle (r3/r4-proven: FETCH 104->18.5MB): 1D grid 768,
//     lid=(bid&7)*96+(bid>>3) bijective; 6 (b,h) pairs/XCD -> K/V L2-resident,
//     staging latency ~200cyc instead of ~900.
//   * all LDS read/write offsets precomputed outside the chunk loop (they are
//     loop-invariant except the (c&1)*4096 buffer toggle) — removes the per-chunk
//     XOR/address recompute that dominated the ~500 VALU insts/wave/chunk.
//   * within each PV kt-step, V-frag loads issue BEFORE the P-frag reads, so the
//     P write->read lgkm wait covers V-read latency.
__global__ __launch_bounds__(256, 3) void attn_fused(const u16* __restrict__ Qh, const u16* __restrict__ Kh,
                                                     const u16* __restrict__ Vt, u16* __restrict__ ctx,
                                                     float* __restrict__ rowsum) {
  __shared__ u16 ldsK[2*64*64];    // [buf][n][8 chunks of 8 u16], chunk XOR-swizzled by n&7
  __shared__ u16 ldsV[2*64*64];    // [buf][d][8 chunks],          swizzled by d&7
  __shared__ u16 ldsP[128*64];     // [m][8 b128-chunks],          swizzled by m&7; wave-private rows
  const int bid = blockIdx.x;
  const int lid = (bid & 7) * 96 + (bid >> 3);   // XCD-contiguous logical id (bijective, 768%8==0)
  const int pair = lid >> 4;            // 0..47 = (b,h)
  const int qt = lid & 15;              // q-tile
  const int h = pair % 12, b = pair / 12;
  const int q0 = qt * 128;
  const int t = threadIdx.x, w = t >> 6, lane = t & 63, quad = lane >> 4, n16 = lane & 15;
  const int sw = n16 & 7;
  const u16* Kbh = Kh + (size_t)b*2048*768 + h*64;
  const u16* Vbh = Vt + (size_t)(b*12 + h)*64*2048;
  auto stage = [&](int c, int bsel) {
#pragma unroll
    for (int jj = 0; jj < 2; ++jj) {
      int slot = jj*256 + t;                // lane-linear LDS dst
      int n = slot >> 3, cg = (slot & 7) ^ (n & 7);
      load_lds16(Kbh + (size_t)(c*64 + n)*768 + cg*8, ldsK + bsel*4096 + slot*8);
      load_lds16(Vbh + (size_t)n*2048 + c*64 + cg*8, ldsV + bsel*4096 + slot*8);
    }
  };
  // loop-invariant LDS element offsets (u16 units)
  int koff[4][2], voff[2][4], prd[2][2], pwr[2], pwc[4];
#pragma unroll
  for (int ni = 0; ni < 4; ++ni) {
    koff[ni][0] = (ni*16 + n16)*64 + ((quad ^ sw) * 8);
    koff[ni][1] = (ni*16 + n16)*64 + (((4 + quad) ^ sw) * 8);
    pwc[ni] = ((ni*2 + (quad >> 1)) ^ sw) * 8;
  }
#pragma unroll
  for (int kt = 0; kt < 2; ++kt)
#pragma unroll
    for (int di = 0; di < 4; ++di)
      voff[kt][di] = (di*16 + n16)*64 + (((kt*4 + quad) ^ sw) * 8);
#pragma unroll
  for (int mi = 0; mi < 2; ++mi) {
    pwr[mi] = (w*32 + mi*16 + n16)*64 + (quad & 1)*4;
    prd[mi][0] = (w*32 + mi*16 + n16)*64 + ((quad ^ sw) * 8);
    prd[mi][1] = (w*32 + mi*16 + n16)*64 + (((4 + quad) ^ sw) * 8);
  }
  bf16x8 qf[2][2];                 // Q frags (pre-scaled by log2e/8) in regs all kernel
#pragma unroll
  for (int mi = 0; mi < 2; ++mi)
#pragma unroll
    for (int ks = 0; ks < 2; ++ks)
      qf[mi][ks] = *(const bf16x8*)(Qh + (size_t)(b*2048 + q0 + w*32 + mi*16 + n16)*768
                                       + h*64 + ks*32 + quad*8);
  // all-ones B fragment: racc += P @ ones gives rowsums on the MFMA pipe,
  // replicated across n16 and already in C-layout rows (quad*4+i).
  union { uint32_t u[4]; bf16x8 v; } onesu = {{0x3F803F80u, 0x3F803F80u, 0x3F803F80u, 0x3F803F80u}};
  const bf16x8 ones = onesu.v;
  f32x4 oacc[2][4] = {};
  f32x4 racc[2] = {};
  stage(0, 0);
#pragma unroll 1
  for (int c = 0; c < 32; ++c) {
    __syncthreads();                        // chunk c staged (vmcnt drain); prior reads of buf[(c+1)&1] done
    if (c < 31) stage(c + 1, (c + 1) & 1);  // prefetch overlaps this chunk's compute
    const int bs = (c & 1) * 4096;
    const u16* K0 = ldsK + bs;
    const u16* V0 = ldsV + bs;
    f32x4 sacc[4][2] = {};
#pragma unroll
    for (int ni = 0; ni < 4; ++ni) {
      bf16x8 kf0 = *(const bf16x8*)(K0 + koff[ni][0]);
      bf16x8 kf1 = *(const bf16x8*)(K0 + koff[ni][1]);
#pragma unroll
      for (int mi = 0; mi < 2; ++mi) {
        sacc[ni][mi] = mfma16(kf0, qf[mi][0], sacc[ni][mi]);   // S^T = K.Q^T
        sacc[ni][mi] = mfma16(kf1, qf[mi][1], sacc[ni][mi]);
      }
    }
    // exp2 (Q pre-scaled -> 1 v_exp each) + native-cast bf16 pack (no VALU rowsum)
#pragma unroll
    for (int mi = 0; mi < 2; ++mi) {
#pragma unroll
      for (int ni = 0; ni < 4; ++ni) {
        float p0 = EXP2(sacc[ni][mi][0]);
        float p1 = EXP2(sacc[ni][mi][1]);
        float p2 = EXP2(sacc[ni][mi][2]);
        float p3 = EXP2(sacc[ni][mi][3]);
        union { __bf16 bx[4]; uint2 v; } pk;
        pk.bx[0] = (__bf16)p0;
        pk.bx[1] = (__bf16)p1;
        pk.bx[2] = (__bf16)p2;
        pk.bx[3] = (__bf16)p3;
        *(uint2*)(ldsP + pwr[mi] + pwc[ni]) = pk.v;
      }
    }
    // PV: A = P (wave-private rows, no barrier), B = V^T chunk; rowsum rides along.
    // V frags issue BEFORE P reads: the P write->read wait covers their latency.
#pragma unroll
    for (int kt = 0; kt < 2; ++kt) {
      bf16x8 vf[4], pf[2];
#pragma unroll
      for (int di = 0; di < 4; ++di)
        vf[di] = *(const bf16x8*)(V0 + voff[kt][di]);
#pragma unroll
      for (int mi = 0; mi < 2; ++mi)
        pf[mi] = *(const bf16x8*)(ldsP + prd[mi][kt]);
#pragma unroll
      for (int mi = 0; mi < 2; ++mi) {
        racc[mi] = mfma16(pf[mi], ones, racc[mi]);
#pragma unroll
        for (int di = 0; di < 4; ++di)
          oacc[mi][di] = mfma16(pf[mi], vf[di], oacc[mi][di]);
      }
    }
  }
  // racc[mi][i] = full rowsum for row quad*4+i (replicated over n16) — matches oacc layout
  float invr[2][4];
#pragma unroll
  for (int mi = 0; mi < 2; ++mi)
#pragma unroll
    for (int i = 0; i < 4; ++i)
      invr[mi][i] = 1.0f / racc[mi][i];
#pragma unroll
  for (int mi = 0; mi < 2; ++mi)
#pragma unroll
    for (int di = 0; di < 4; ++di)
#pragma unroll
      for (int i = 0; i < 4; ++i) {
        size_t r = (size_t)b*2048 + q0 + w*32 + mi*16 + quad*4 + i;
        int cc = h*64 + di*16 + n16;
        ctx[r*768 + cc] = f2bf(oacc[mi][di][i] * invr[mi][i]);
      }
  if (h == 0 && n16 == 0) {
#pragma unroll
    for (int mi = 0; mi < 2; ++mi)
#pragma unroll
      for (int i = 0; i < 4; ++i)
        rowsum[b*2048 + q0 + w*32 + mi*16 + quad*4 + i] = racc[mi][i];
  }
}

// ---------------- attn[:,0,:,:]: recompute QK^T for h=0, scale by 1/rowsum ----------------
__global__ __launch_bounds__(256) void attn_h0(const u16* __restrict__ Qh, const u16* __restrict__ Kh,
                                               const float* __restrict__ rowsum, float* __restrict__ aout) {
  __shared__ u16 ldsK[128*64];
  const int qt = blockIdx.x, kt = blockIdx.y, b = blockIdx.z;
  const int t = threadIdx.x, w = t >> 6, lane = t & 63, quad = lane >> 4, n16 = lane & 15;
  const int q0 = qt * 128;
  const u16* Kbh = Kh + (size_t)b*2048*768;  // h = 0
  bf16x8 qf[2][2];
#pragma unroll
  for (int mi = 0; mi < 2; ++mi)
#pragma unroll
    for (int ks = 0; ks < 2; ++ks)
      qf[mi][ks] = *(const bf16x8*)(Qh + (size_t)(b*2048 + q0 + w*32 + mi*16 + n16)*768
                                       + ks*32 + quad*8);
#pragma unroll
  for (int j = 0; j < 4; ++j) {
    int slot = j*256 + w*64 + lane;
    int n = slot >> 3, cs = slot & 7, cg = cs ^ (n & 7);
    load_lds16(Kbh + (size_t)(kt*128 + n)*768 + cg*8, ldsK + slot*8);
  }
  __syncthreads();
  f32x4 sacc[2][8] = {};
#pragma unroll
  for (int ni = 0; ni < 8; ++ni) {
    int n = ni*16 + n16;
    bf16x8 kf0 = *(const bf16x8*)(ldsK + n*64 + ((quad)     ^ (n & 7))*8);
    bf16x8 kf1 = *(const bf16x8*)(ldsK + n*64 + ((4 + quad) ^ (n & 7))*8);
#pragma unroll
    for (int mi = 0; mi < 2; ++mi) {
      sacc[mi][ni] = mfma16(qf[mi][0], kf0, sacc[mi][ni]);
      sacc[mi][ni] = mfma16(qf[mi][1], kf1, sacc[mi][ni]);
    }
  }
  float inv[2][4];
#pragma unroll
  for (int mi = 0; mi < 2; ++mi)
#pragma unroll
    for (int i = 0; i < 4; ++i)
      inv[mi][i] = 1.0f / rowsum[b*2048 + q0 + w*32 + mi*16 + quad*4 + i];
#pragma unroll
  for (int mi = 0; mi < 2; ++mi)
#pragma unroll
    for (int ni = 0; ni < 8; ++ni)
#pragma unroll
      for (int i = 0; i < 4; ++i) {
        size_t r = (size_t)b*2048 + q0 + w*32 + mi*16 + quad*4 + i;
        size_t cc = (size_t)kt*128 + ni*16 + n16;
        aout[r*2048 + cc] = EXP2(sacc[mi][ni][i]) * inv[mi][i];   // Qh pre-scaled
      }
}

extern "C" void kernel_launch(void* const* d_in, const int* in_sizes, int n_in,
                              void* d_out, int out_size, void* d_ws, size_t ws_size,
                              hipStream_t stream) {
  (void)in_sizes; (void)n_in; (void)out_size; (void)ws_size;
  const float* q  = (const float*)d_in[0];
  const float* k  = (const float*)d_in[1];
  const float* v  = (const float*)d_in[2];
  const float* wq = (const float*)d_in[3];
  const float* wk = (const float*)d_in[4];
  const float* wv = (const float*)d_in[5];
  const float* wd = (const float*)d_in[6];
  const float* bd = (const float*)d_in[7];

  // ws layout (u16 elements), high-water ~67.7 MB:
  //   qb -> Vt   (qb dead after fused QK projection; V-gemm writes Vt there)
  //   kb -> ctx  (kb dead after fused QK projection)
  u16* ws  = (u16*)d_ws;
  u16* qb  = ws;                       // rows 0..8191  of fused QK A-matrix
  u16* kb  = ws + (size_t)BSD;         // rows 8192..16383
  u16* vb  = ws + 2L*BSD;
  u16* wqb = ws + 3L*BSD;              // wq, wk contiguous (BSEL indexing)
  u16* wvb = wqb + 2L*WSZ;
  u16* wdb = wqb + 3L*WSZ;
  u16* Qh  = ws + 3L*BSD + 4L*WSZ;     // Qh, Kh contiguous (fused QK C-matrix)
  u16* Kh  = Qh + (size_t)BSD;
  float* rsum = (float*)(Kh + (size_t)BSD);
  u16* Vt  = qb;
  u16* ctx = kb;
  float* out  = (float*)d_out;
  float* aout = out + (size_t)BSD;

  convert_all<<<dim3(10368), 256, 0, stream>>>(q, k, v, wq, wk, wv, wd, ws);
  // fused Q+K projection (Q pre-scaled by log2e/8), 768 blocks = 3/CU even
  gemm_bt<0,1><<<dim3(128, 6), 256, 0, stream>>>(qb, wqb, Qh, nullptr, nullptr, 16384, 768, 768, QSCALE);
  // V projection with fused transpose into Vt
  gemm_bt<2,0><<<dim3(64, 6), 256, 0, stream>>>(vb, wvb, Vt, nullptr, nullptr, 8192, 768, 768, 1.0f);
  attn_fused<<<dim3(768), 256, 0, stream>>>(Qh, Kh, Vt, ctx, rsum);
  attn_h0<<<dim3(16, 16, 4), 256, 0, stream>>>(Qh, Kh, rsum, aout);
  gemm_bt<1,0><<<dim3(64, 6), 256, 0, stream>>>(ctx, wdb, nullptr, out, bd, 8192, 768, 768, 1.0f);
}

// Round 6
// 309.636 us; speedup vs baseline: 1.0621x; 1.0002x over previous
//
#include <hip/hip_runtime.h>
#include <stdint.h>

typedef unsigned short u16;
typedef __attribute__((ext_vector_type(8))) __bf16 bf16x8;
typedef __attribute__((ext_vector_type(4))) float f32x4;

#define BSD 6291456   // 4*2048*768
#define WSZ 589824    // 768*768
#define QSCALE 0.18033688011112042f   // log2(e)/8, folded into Q projection

#if __has_builtin(__builtin_amdgcn_exp2f)
#define EXP2(x) __builtin_amdgcn_exp2f(x)
#else
#define EXP2(x) __builtin_exp2f(x)
#endif

__device__ __forceinline__ uint32_t fbits(float f) {
  union { float f; uint32_t u; } v; v.f = f; return v.u;
}
__device__ __forceinline__ u16 f2bf(float f) {           // RNE (epilogue scalar use only)
  uint32_t u = fbits(f);
  return (u16)((u + 0x7fff + ((u >> 16) & 1)) >> 16);
}
// round-to-nearest (half-up) bf16 pack of two floats via v_perm_b32: 3 insts / 2 values
__device__ __forceinline__ uint32_t pack_bf16rn(float lo, float hi) {
  return __builtin_amdgcn_perm(fbits(hi) + 0x8000u, fbits(lo) + 0x8000u, 0x07060302u);
}

__device__ __forceinline__ void load_lds16(const u16* g, u16* l) {
  __builtin_amdgcn_global_load_lds((__attribute__((address_space(1))) void*)(void*)g,
                                   (__attribute__((address_space(3))) void*)l, 16, 0, 0);
}

__device__ __forceinline__ f32x4 mfma16(bf16x8 a, bf16x8 b, f32x4 c) {
  return __builtin_amdgcn_mfma_f32_16x16x32_bf16(a, b, c, 0, 0, 0);
}

// ---------------- fp32 -> bf16 conversion of q,k,v + 4 weights ----------------
__global__ void convert_all(const float* __restrict__ q, const float* __restrict__ k,
                            const float* __restrict__ v, const float* __restrict__ wq,
                            const float* __restrict__ wk, const float* __restrict__ wv,
                            const float* __restrict__ wd, u16* __restrict__ ws) {
  long e = ((long)blockIdx.x * blockDim.x + threadIdx.x) * 8;
  const float* src;
  if (e < (long)BSD) src = q + e;
  else if (e < 2L*BSD) src = k + (e - (long)BSD);
  else if (e < 3L*BSD) src = v + (e - 2L*BSD);
  else {
    long r = e - 3L*BSD;
    if (r < (long)WSZ) src = wq + r;
    else if (r < 2L*WSZ) src = wk + (r - (long)WSZ);
    else if (r < 3L*WSZ) src = wv + (r - 2L*WSZ);
    else src = wd + (r - 3L*WSZ);
  }
  float4 f0 = ((const float4*)src)[0];
  float4 f1 = ((const float4*)src)[1];
  uint4 o;
  o.x = pack_bf16rn(f0.x, f0.y);
  o.y = pack_bf16rn(f0.z, f0.w);
  o.z = pack_bf16rn(f1.x, f1.y);
  o.w = pack_bf16rn(f1.z, f1.w);
  *(uint4*)(ws + e) = o;
}

// ---------------- C = A @ B^T (m97-style 128x128xBK32) ----------------
// MODE 0: bf16 C = val*oscale, row-major [M,N]
// MODE 1: f32  C = val + bias[c]
// MODE 2: bf16 written TRANSPOSED into Vt [B=4, H=12, 64, 2048] (packed 8B stores)
// BSEL 1: fused Q+K projection — rows >= 8192 use Bw+WSZ (wk) and scale 1
// Round-6: XCD-aware block remap. Dispatch linearizes x-fastest, XCDs round-robin
// on linear id, so the gy blocks sharing one A-row-panel (196KB) used to land on
// different XCDs -> A refetched from HBM per n-block. Remap gives each XCD a
// contiguous run of full row-panel groups -> A is L2-resident per XCD.
// Bijective iff nb%8==0 (all launches: 768/384/384); guarded fallback otherwise.
template<int MODE, int BSEL>
__global__ __launch_bounds__(256) void gemm_bt(const u16* __restrict__ A, const u16* __restrict__ Bw,
                                               u16* __restrict__ Cb, float* __restrict__ Cf,
                                               const float* __restrict__ bias,
                                               int M, int N, int K, float oscale) {
  __shared__ u16 ldsA[128*32];
  __shared__ u16 ldsB[128*32];
  const int t = threadIdx.x, w = t >> 6, lane = t & 63, quad = lane >> 4, n16 = lane & 15;
  const int gx = gridDim.x, gy = gridDim.y;
  const int nb = gx * gy;
  int bx, by;
  if ((nb & 7) == 0) {
    int bid = (int)blockIdx.y * gx + (int)blockIdx.x;   // hw linear dispatch id
    int lid = (bid & 7) * (nb >> 3) + (bid >> 3);       // XCD-contiguous logical id
    bx = lid / gy; by = lid % gy;                       // same-bx blocks adjacent
  } else {
    bx = blockIdx.x; by = blockIdx.y;
  }
  const int m0 = bx * 128, n0 = by * 128;
  const int wr = (w >> 1) * 64, wc = (w & 1) * 64;
  const u16* Bm = Bw;
  float sc = oscale;
  if (BSEL && m0 >= 8192) { Bm = Bw + WSZ; sc = 1.0f; }
  f32x4 acc[4][4] = {};
  for (int k0 = 0; k0 < K; k0 += 32) {
    __syncthreads();
#pragma unroll
    for (int j = 0; j < 2; ++j) {
      int slot = j*256 + w*64 + lane;        // lane-linear LDS dst
      int row = slot >> 2, ch = slot & 3;
      load_lds16(A  + (size_t)(m0 + row)*K + k0 + ch*8, ldsA + slot*8);
      load_lds16(Bm + (size_t)(n0 + row)*K + k0 + ch*8, ldsB + slot*8);
    }
    __syncthreads();
    bf16x8 af[4], bf[4];
#pragma unroll
    for (int i = 0; i < 4; ++i) {
      af[i] = *(const bf16x8*)(ldsA + (wr + i*16 + n16)*32 + quad*8);
      bf[i] = *(const bf16x8*)(ldsB + (wc + i*16 + n16)*32 + quad*8);
    }
#pragma unroll
    for (int mi = 0; mi < 4; ++mi)
#pragma unroll
      for (int ni = 0; ni < 4; ++ni)
        acc[mi][ni] = mfma16(af[mi], bf[ni], acc[mi][ni]);
  }
#pragma unroll
  for (int mi = 0; mi < 4; ++mi)
#pragma unroll
    for (int ni = 0; ni < 4; ++ni) {
      if (MODE == 2) {
        int c = n0 + wc + ni*16 + n16;                 // feature 0..767
        int hh = c >> 6, d = c & 63;
        int m = m0 + wr + mi*16 + quad*4;              // 4 consecutive tokens
        int bI = m >> 11, s = m & 2047;
        uint2 pk;
        pk.x = pack_bf16rn(acc[mi][ni][0], acc[mi][ni][1]);
        pk.y = pack_bf16rn(acc[mi][ni][2], acc[mi][ni][3]);
        *(uint2*)(Cb + ((size_t)(bI*12 + hh)*64 + d)*2048 + s) = pk;
      } else {
#pragma unroll
        for (int i = 0; i < 4; ++i) {
          size_t r = (size_t)m0 + wr + mi*16 + quad*4 + i;   // C/D: row=(lane>>4)*4+i
          size_t c = (size_t)n0 + wc + ni*16 + n16;          //      col=lane&15
          float val = acc[mi][ni][i];
          if (MODE == 1) Cf[r*(size_t)N + c] = val + bias[c];
          else           Cb[r*(size_t)N + c] = f2bf(val * sc);
        }
      }
    }
}

// ---------------- fused attention, round 9: r5 + s_setprio on MFMA clusters ----
// r5 audit: per-CU per chunk (5150cyc wall): LDS unit ~67% busy, VALU 35%, MFMA
// issue ~10%; 3 independent blocks/CU. setprio(1) around the MFMA clusters lets
// an MFMA-entering wave preempt staging/VALU waves of the OTHER resident blocks
// (m191 precedent: +4-7% on attn with independent wave streams; m190's null was
// a single lockstep block — not our case).
__global__ __launch_bounds__(256, 3) void attn_fused(const u16* __restrict__ Qh, const u16* __restrict__ Kh,
                                                     const u16* __restrict__ Vt, u16* __restrict__ ctx,
                                                     float* __restrict__ rowsum) {
  __shared__ u16 ldsK[2*64*64];    // [buf][n][8 chunks of 8 u16], chunk XOR-swizzled by n&7
  __shared__ u16 ldsV[2*64*64];    // [buf][d][8 chunks],          swizzled by d&7
  __shared__ u16 ldsP[128*64];     // [m][8 b128-chunks],          swizzled by m&7; wave-private rows
  const int bid = blockIdx.x;
  const int lid = (bid & 7) * 96 + (bid >> 3);   // XCD-contiguous logical id (bijective, 768%8==0)
  const int pair = lid >> 4;            // 0..47 = (b,h)
  const int qt = lid & 15;              // q-tile
  const int h = pair % 12, b = pair / 12;
  const int q0 = qt * 128;
  const int t = threadIdx.x, w = t >> 6, lane = t & 63, quad = lane >> 4, n16 = lane & 15;
  const int sw = n16 & 7;
  const u16* Kbh = Kh + (size_t)b*2048*768 + h*64;
  const u16* Vbh = Vt + (size_t)(b*12 + h)*64*2048;
  auto stage = [&](int c, int bsel) {
#pragma unroll
    for (int jj = 0; jj < 2; ++jj) {
      int slot = jj*256 + t;                // lane-linear LDS dst
      int n = slot >> 3, cg = (slot & 7) ^ (n & 7);
      load_lds16(Kbh + (size_t)(c*64 + n)*768 + cg*8, ldsK + bsel*4096 + slot*8);
      load_lds16(Vbh + (size_t)n*2048 + c*64 + cg*8, ldsV + bsel*4096 + slot*8);
    }
  };
  // loop-invariant LDS element offsets (u16 units)
  int koff[4][2], voff[2][4], prd[2][2], pwr[2], pwc[4];
#pragma unroll
  for (int ni = 0; ni < 4; ++ni) {
    koff[ni][0] = (ni*16 + n16)*64 + ((quad ^ sw) * 8);
    koff[ni][1] = (ni*16 + n16)*64 + (((4 + quad) ^ sw) * 8);
    pwc[ni] = ((ni*2 + (quad >> 1)) ^ sw) * 8;
  }
#pragma unroll
  for (int kt = 0; kt < 2; ++kt)
#pragma unroll
    for (int di = 0; di < 4; ++di)
      voff[kt][di] = (di*16 + n16)*64 + (((kt*4 + quad) ^ sw) * 8);
#pragma unroll
  for (int mi = 0; mi < 2; ++mi) {
    pwr[mi] = (w*32 + mi*16 + n16)*64 + (quad & 1)*4;
    prd[mi][0] = (w*32 + mi*16 + n16)*64 + ((quad ^ sw) * 8);
    prd[mi][1] = (w*32 + mi*16 + n16)*64 + (((4 + quad) ^ sw) * 8);
  }
  bf16x8 qf[2][2];                 // Q frags (pre-scaled by log2e/8) in regs all kernel
#pragma unroll
  for (int mi = 0; mi < 2; ++mi)
#pragma unroll
    for (int ks = 0; ks < 2; ++ks)
      qf[mi][ks] = *(const bf16x8*)(Qh + (size_t)(b*2048 + q0 + w*32 + mi*16 + n16)*768
                                       + h*64 + ks*32 + quad*8);
  // all-ones B fragment: racc += P @ ones gives rowsums on the MFMA pipe,
  // replicated across n16 and already in C-layout rows (quad*4+i).
  union { uint32_t u[4]; bf16x8 v; } onesu = {{0x3F803F80u, 0x3F803F80u, 0x3F803F80u, 0x3F803F80u}};
  const bf16x8 ones = onesu.v;
  f32x4 oacc[2][4] = {};
  f32x4 racc[2] = {};
  stage(0, 0);
#pragma unroll 1
  for (int c = 0; c < 32; ++c) {
    __syncthreads();                        // chunk c staged (vmcnt drain); prior reads of buf[(c+1)&1] done
    if (c < 31) stage(c + 1, (c + 1) & 1);  // prefetch overlaps this chunk's compute
    const int bs = (c & 1) * 4096;
    const u16* K0 = ldsK + bs;
    const u16* V0 = ldsV + bs;
    f32x4 sacc[4][2] = {};
    __builtin_amdgcn_s_setprio(1);
#pragma unroll
    for (int ni = 0; ni < 4; ++ni) {
      bf16x8 kf0 = *(const bf16x8*)(K0 + koff[ni][0]);
      bf16x8 kf1 = *(const bf16x8*)(K0 + koff[ni][1]);
#pragma unroll
      for (int mi = 0; mi < 2; ++mi) {
        sacc[ni][mi] = mfma16(kf0, qf[mi][0], sacc[ni][mi]);   // S^T = K.Q^T
        sacc[ni][mi] = mfma16(kf1, qf[mi][1], sacc[ni][mi]);
      }
    }
    __builtin_amdgcn_s_setprio(0);
    // exp2 (Q pre-scaled -> 1 v_exp each) + native-cast bf16 pack (no VALU rowsum)
#pragma unroll
    for (int mi = 0; mi < 2; ++mi) {
#pragma unroll
      for (int ni = 0; ni < 4; ++ni) {
        float p0 = EXP2(sacc[ni][mi][0]);
        float p1 = EXP2(sacc[ni][mi][1]);
        float p2 = EXP2(sacc[ni][mi][2]);
        float p3 = EXP2(sacc[ni][mi][3]);
        union { __bf16 bx[4]; uint2 v; } pk;
        pk.bx[0] = (__bf16)p0;
        pk.bx[1] = (__bf16)p1;
        pk.bx[2] = (__bf16)p2;
        pk.bx[3] = (__bf16)p3;
        *(uint2*)(ldsP + pwr[mi] + pwc[ni]) = pk.v;
      }
    }
    // PV: A = P (wave-private rows, no barrier), B = V^T chunk; rowsum rides along.
    // V frags issue BEFORE P reads: the P write->read wait covers their latency.
#pragma unroll
    for (int kt = 0; kt < 2; ++kt) {
      bf16x8 vf[4], pf[2];
#pragma unroll
      for (int di = 0; di < 4; ++di)
        vf[di] = *(const bf16x8*)(V0 + voff[kt][di]);
#pragma unroll
      for (int mi = 0; mi < 2; ++mi)
        pf[mi] = *(const bf16x8*)(ldsP + prd[mi][kt]);
      __builtin_amdgcn_s_setprio(1);
#pragma unroll
      for (int mi = 0; mi < 2; ++mi) {
        racc[mi] = mfma16(pf[mi], ones, racc[mi]);
#pragma unroll
        for (int di = 0; di < 4; ++di)
          oacc[mi][di] = mfma16(pf[mi], vf[di], oacc[mi][di]);
      }
      __builtin_amdgcn_s_setprio(0);
    }
  }
  // racc[mi][i] = full rowsum for row quad*4+i (replicated over n16) — matches oacc layout
  float invr[2][4];
#pragma unroll
  for (int mi = 0; mi < 2; ++mi)
#pragma unroll
    for (int i = 0; i < 4; ++i)
      invr[mi][i] = 1.0f / racc[mi][i];
#pragma unroll
  for (int mi = 0; mi < 2; ++mi)
#pragma unroll
    for (int di = 0; di < 4; ++di)
#pragma unroll
      for (int i = 0; i < 4; ++i) {
        size_t r = (size_t)b*2048 + q0 + w*32 + mi*16 + quad*4 + i;
        int cc = h*64 + di*16 + n16;
        ctx[r*768 + cc] = f2bf(oacc[mi][di][i] * invr[mi][i]);
      }
  if (h == 0 && n16 == 0) {
#pragma unroll
    for (int mi = 0; mi < 2; ++mi)
#pragma unroll
      for (int i = 0; i < 4; ++i)
        rowsum[b*2048 + q0 + w*32 + mi*16 + quad*4 + i] = racc[mi][i];
  }
}

// ---------------- attn[:,0,:,:]: recompute QK^T for h=0, scale by 1/rowsum ----------------
__global__ __launch_bounds__(256) void attn_h0(const u16* __restrict__ Qh, const u16* __restrict__ Kh,
                                               const float* __restrict__ rowsum, float* __restrict__ aout) {
  __shared__ u16 ldsK[128*64];
  const int qt = blockIdx.x, kt = blockIdx.y, b = blockIdx.z;
  const int t = threadIdx.x, w = t >> 6, lane = t & 63, quad = lane >> 4, n16 = lane & 15;
  const int q0 = qt * 128;
  const u16* Kbh = Kh + (size_t)b*2048*768;  // h = 0
  bf16x8 qf[2][2];
#pragma unroll
  for (int mi = 0; mi < 2; ++mi)
#pragma unroll
    for (int ks = 0; ks < 2; ++ks)
      qf[mi][ks] = *(const bf16x8*)(Qh + (size_t)(b*2048 + q0 + w*32 + mi*16 + n16)*768
                                       + ks*32 + quad*8);
#pragma unroll
  for (int j = 0; j < 4; ++j) {
    int slot = j*256 + w*64 + lane;
    int n = slot >> 3, cs = slot & 7, cg = cs ^ (n & 7);
    load_lds16(Kbh + (size_t)(kt*128 + n)*768 + cg*8, ldsK + slot*8);
  }
  __syncthreads();
  f32x4 sacc[2][8] = {};
#pragma unroll
  for (int ni = 0; ni < 8; ++ni) {
    int n = ni*16 + n16;
    bf16x8 kf0 = *(const bf16x8*)(ldsK + n*64 + ((quad)     ^ (n & 7))*8);
    bf16x8 kf1 = *(const bf16x8*)(ldsK + n*64 + ((4 + quad) ^ (n & 7))*8);
#pragma unroll
    for (int mi = 0; mi < 2; ++mi) {
      sacc[mi][ni] = mfma16(qf[mi][0], kf0, sacc[mi][ni]);
      sacc[mi][ni] = mfma16(qf[mi][1], kf1, sacc[mi][ni]);
    }
  }
  float inv[2][4];
#pragma unroll
  for (int mi = 0; mi < 2; ++mi)
#pragma unroll
    for (int i = 0; i < 4; ++i)
      inv[mi][i] = 1.0f / rowsum[b*2048 + q0 + w*32 + mi*16 + quad*4 + i];
#pragma unroll
  for (int mi = 0; mi < 2; ++mi)
#pragma unroll
    for (int ni = 0; ni < 8; ++ni)
#pragma unroll
      for (int i = 0; i < 4; ++i) {
        size_t r = (size_t)b*2048 + q0 + w*32 + mi*16 + quad*4 + i;
        size_t cc = (size_t)kt*128 + ni*16 + n16;
        aout[r*2048 + cc] = EXP2(sacc[mi][ni][i]) * inv[mi][i];   // Qh pre-scaled
      }
}

extern "C" void kernel_launch(void* const* d_in, const int* in_sizes, int n_in,
                              void* d_out, int out_size, void* d_ws, size_t ws_size,
                              hipStream_t stream) {
  (void)in_sizes; (void)n_in; (void)out_size; (void)ws_size;
  const float* q  = (const float*)d_in[0];
  const float* k  = (const float*)d_in[1];
  const float* v  = (const float*)d_in[2];
  const float* wq = (const float*)d_in[3];
  const float* wk = (const float*)d_in[4];
  const float* wv = (const float*)d_in[5];
  const float* wd = (const float*)d_in[6];
  const float* bd = (const float*)d_in[7];

  // ws layout (u16 elements), high-water ~67.7 MB:
  //   qb -> Vt   (qb dead after fused QK projection; V-gemm writes Vt there)
  //   kb -> ctx  (kb dead after fused QK projection)
  u16* ws  = (u16*)d_ws;
  u16* qb  = ws;                       // rows 0..8191  of fused QK A-matrix
  u16* kb  = ws + (size_t)BSD;         // rows 8192..16383
  u16* vb  = ws + 2L*BSD;
  u16* wqb = ws + 3L*BSD;              // wq, wk contiguous (BSEL indexing)
  u16* wvb = wqb + 2L*WSZ;
  u16* wdb = wqb + 3L*WSZ;
  u16* Qh  = ws + 3L*BSD + 4L*WSZ;     // Qh, Kh contiguous (fused QK C-matrix)
  u16* Kh  = Qh + (size_t)BSD;
  float* rsum = (float*)(Kh + (size_t)BSD);
  u16* Vt  = qb;
  u16* ctx = kb;
  float* out  = (float*)d_out;
  float* aout = out + (size_t)BSD;

  convert_all<<<dim3(10368), 256, 0, stream>>>(q, k, v, wq, wk, wv, wd, ws);
  // fused Q+K projection (Q pre-scaled by log2e/8), 768 blocks = 3/CU even
  gemm_bt<0,1><<<dim3(128, 6), 256, 0, stream>>>(qb, wqb, Qh, nullptr, nullptr, 16384, 768, 768, QSCALE);
  // V projection with fused transpose into Vt
  gemm_bt<2,0><<<dim3(64, 6), 256, 0, stream>>>(vb, wvb, Vt, nullptr, nullptr, 8192, 768, 768, 1.0f);
  attn_fused<<<dim3(768), 256, 0, stream>>>(Qh, Kh, Vt, ctx, rsum);
  attn_h0<<<dim3(16, 16, 4), 256, 0, stream>>>(Qh, Kh, rsum, aout);
  gemm_bt<1,0><<<dim3(64, 6), 256, 0, stream>>>(ctx, wdb, nullptr, out, bd, 8192, 768, 768, 1.0f);
}